// Round 1
// baseline (599.592 us; speedup 1.0000x reference)
//
#include <hip/hip_runtime.h>
#include <math.h>

#define BT    256
#define S_LEN 4096
#define FE    64
#define NLEV  9
#define NROWS 8192          // 128 * 64
#define DTOT  4138          // sum of detail lengths

// db4 reconstruction filters (reference's REC_LO / REC_HI).
// Forward conv a[i] = sum_j xe[2i+1+j]*RL[j]; d[i] = sum_j xe[2i+1+j]*RH[j]
// (DEC_* are reversed REC_*, and convolve flips again -> RL/RH directly.)
__device__ __constant__ float RL[8] = {
     0.23037781330885523f,  0.7148465705525415f,   0.6308807679295904f,
    -0.02798376941698385f, -0.18703481171888114f,  0.030841381835986965f,
     0.032883011666982945f, -0.010597401784997278f };
__device__ __constant__ float RH[8] = {
    -0.010597401784997278f, -0.032883011666982945f, 0.030841381835986965f,
     0.18703481171888114f,  -0.02798376941698385f, -0.6308807679295904f,
     0.7148465705525415f,   -0.23037781330885523f };

__device__ __constant__ int SIZES[10] = {4096,2051,1029,518,262,134,70,38,22,14};
__device__ __constant__ int DOFF[10]  = {0,0,2051,3080,3598,3860,3994,4064,4102,4124};

__device__ __forceinline__ float softf(float c, float thr) {
    float a = fabsf(c) - thr;
    return a > 0.0f ? copysignf(a, c) : 0.0f;
}

__global__ __launch_bounds__(BT) void dwt_enh_kernel(const float* __restrict__ x,
                                                     float* __restrict__ out) {
    const int tid = threadIdx.x;
    // XCD-chunked swizzle: XCD k (bid%8) gets contiguous rows [k*1024,(k+1)*1024)
    const int m = ((blockIdx.x & 7) << 10) | (blockIdx.x >> 3);
    const int b = m >> 6, f = m & 63;
    const float* __restrict__ rowp = x   + (size_t)b * (S_LEN * FE) + f;
    float* __restrict__       orow = out + (size_t)b * (S_LEN * FE) + f;

    __shared__ __align__(16) float bufA[4096];
    __shared__ __align__(16) float bufB[2052];
    __shared__ float dets[DTOT];
    __shared__ double redS[BT / 64], redQ[BT / 64];
    __shared__ float s_thr;

    // ---- load row (strided global -> LDS) ----
    for (int s = tid; s < S_LEN; s += BT) bufA[s] = rowp[(size_t)s * FE];
    __syncthreads();

    // ---- forward DWT, 9 levels ----
    float* src = bufA;
    float* dst = bufB;
    int n = S_LEN;
    for (int lev = 1; lev <= NLEV; ++lev) {
        const int na = (n + 7) >> 1;
        float* __restrict__ dd = dets + DOFF[lev];
        const int npair = (na + 1) >> 1;
        for (int ii = tid; ii < npair; ii += BT) {
            // window w[j] = xe[4*ii+1+j] = src[map(4*ii+j-6)], j=0..9
            float w[10];
            if (ii >= 2 && 4 * ii <= n - 4) {
                // interior: contiguous, 16B-aligned -> 3x ds_read_b128
                const float4* p = (const float4*)(src + 4 * ii - 8);
                float4 v0 = p[0], v1 = p[1], v2 = p[2];
                w[0]=v0.z; w[1]=v0.w; w[2]=v1.x; w[3]=v1.y; w[4]=v1.z;
                w[5]=v1.w; w[6]=v2.x; w[7]=v2.y; w[8]=v2.z; w[9]=v2.w;
            } else {
                #pragma unroll
                for (int j = 0; j < 10; ++j) {
                    int q = 4 * ii + j - 6;
                    q = (q < 0) ? ~q : q;            // symmetric left: -q-1
                    q = (q >= n) ? (2 * n - 1 - q) : q; // symmetric right
                    w[j] = src[q];
                }
            }
            float a0 = 0.f, d0 = 0.f, a1 = 0.f, d1 = 0.f;
            #pragma unroll
            for (int j = 0; j < 8; ++j) {
                a0 = fmaf(w[j],     RL[j], a0);
                d0 = fmaf(w[j],     RH[j], d0);
                a1 = fmaf(w[j + 2], RL[j], a1);
                d1 = fmaf(w[j + 2], RH[j], d1);
            }
            const int i0 = 2 * ii;
            dst[i0] = a0; dd[i0] = d0;
            if (i0 + 1 < na) { dst[i0 + 1] = a1; dd[i0 + 1] = d1; }
        }
        __syncthreads();
        float* t = src; src = dst; dst = t;
        n = na;
    }
    // a9 (len 14) now in `src` (== bufB)

    // ---- threshold = std(d1) * sqrt(2*ln(S)) ----
    {
        double s = 0.0, q = 0.0;
        for (int i = tid; i < 2051; i += BT) {
            double v = (double)dets[i];
            s += v; q += v * v;
        }
        #pragma unroll
        for (int off = 32; off > 0; off >>= 1) {
            s += __shfl_down(s, off, 64);
            q += __shfl_down(q, off, 64);
        }
        const int wid = tid >> 6, lane = tid & 63;
        if (lane == 0) { redS[wid] = s; redQ[wid] = q; }
        __syncthreads();
        if (tid == 0) {
            double S = 0.0, Q = 0.0;
            #pragma unroll
            for (int w2 = 0; w2 < BT / 64; ++w2) { S += redS[w2]; Q += redQ[w2]; }
            const double nd = 2051.0;
            double mean = S / nd;
            double var  = Q / nd - mean * mean;
            if (var < 0.0) var = 0.0;
            s_thr = (float)(sqrt(var) * sqrt(2.0 * log((double)S_LEN)));
        }
        __syncthreads();
    }
    const float thr = s_thr;

    // ---- soft-threshold all details + final approx ----
    for (int i = tid; i < DTOT; i += BT) dets[i] = softf(dets[i], thr);
    if (tid < 14) src[tid] = softf(src[tid], thr);
    __syncthreads();

    // ---- inverse DWT, 9 levels ----
    // out[2ii]   = sum_u A[ii+u]*RL[6-2u] + D[ii+u]*RH[6-2u]
    // out[2ii+1] = sum_u A[ii+u]*RL[7-2u] + D[ii+u]*RH[7-2u]
    // trim (len(a)==len(d)+1) is automatic: we only read A[0..nn+2], nn=len(d)
    float* A = src;                       // bufB
    float* O = (A == bufA) ? bufB : bufA; // bufA
    for (int lev = NLEV; lev >= 1; --lev) {
        const int nn = SIZES[lev];
        const float* __restrict__ D = dets + DOFF[lev];
        const int npair = nn - 3;         // output length 2*nn-6
        for (int ii = tid; ii < npair; ii += BT) {
            float a0 = A[ii], a1 = A[ii + 1], a2 = A[ii + 2], a3 = A[ii + 3];
            float e0 = D[ii], e1 = D[ii + 1], e2 = D[ii + 2], e3 = D[ii + 3];
            float se = a0 * RL[6] + a1 * RL[4] + a2 * RL[2] + a3 * RL[0]
                     + e0 * RH[6] + e1 * RH[4] + e2 * RH[2] + e3 * RH[0];
            float so = a0 * RL[7] + a1 * RL[5] + a2 * RL[3] + a3 * RL[1]
                     + e0 * RH[7] + e1 * RH[5] + e2 * RH[3] + e3 * RH[1];
            O[2 * ii]     = se;
            O[2 * ii + 1] = so;
        }
        __syncthreads();
        float* t = A; A = O; O = t;
    }
    // reconstructed row (4096) in A (== bufA)

    // ---- store (LDS -> strided global) ----
    for (int s = tid; s < S_LEN; s += BT) orow[(size_t)s * FE] = A[s];
}

extern "C" void kernel_launch(void* const* d_in, const int* in_sizes, int n_in,
                              void* d_out, int out_size, void* d_ws, size_t ws_size,
                              hipStream_t stream) {
    const float* x = (const float*)d_in[0];
    float* out = (float*)d_out;
    hipLaunchKernelGGL(dwt_enh_kernel, dim3(NROWS), dim3(BT), 0, stream, x, out);
}

// Round 5
// 388.243 us; speedup vs baseline: 1.5444x; 1.5444x over previous
//
#include <hip/hip_runtime.h>
#include <math.h>

#define BT    256
#define DT    512
#define S_LEN 4096
#define FE    64
#define NLEV  9
#define NROWS 8192          // 128 * 64
#define DTOT  4138          // sum of detail lengths (fallback kernel)

// db4 filters. Forward: a[i] = sum_j xe[2i+1+j]*RL[j]; d[i] = sum_j xe[2i+1+j]*RH[j]
__device__ __constant__ float RL[8] = {
     0.23037781330885523f,  0.7148465705525415f,   0.6308807679295904f,
    -0.02798376941698385f, -0.18703481171888114f,  0.030841381835986965f,
     0.032883011666982945f, -0.010597401784997278f };
__device__ __constant__ float RH[8] = {
    -0.010597401784997278f, -0.032883011666982945f, 0.030841381835986965f,
     0.18703481171888114f,  -0.02798376941698385f, -0.6308807679295904f,
     0.7148465705525415f,   -0.23037781330885523f };

__device__ __constant__ int SIZES[10] = {4096,2051,1029,518,262,134,70,38,22,14};
// fallback kernel's dets offsets
__device__ __constant__ int DOFF[10]  = {0,0,2051,3080,3598,3860,3994,4064,4102,4124};
// d2..d9 offsets inside A0's dead tail [2009:4096] (main kernel)
__device__ __constant__ int DOFF2[10] = {0,0,2009,3038,3556,3818,3952,4022,4060,4082};

__device__ __forceinline__ float softf(float c, float thr) {
    float a = fabsf(c) - thr;
    return a > 0.0f ? copysignf(a, c) : 0.0f;
}

// ---------------- kernel 1: x (B,S,F) -> stage (B*F, S) ----------------
__global__ __launch_bounds__(BT) void transpose_in(const float* __restrict__ x,
                                                   float* __restrict__ stage) {
    const int b  = blockIdx.x >> 6;
    const int s0 = (blockIdx.x & 63) << 6;
    const int tid = threadIdx.x;
    __shared__ float t[64][65];          // t[s][f]

    // tile (64 s) x (64 f) = 4096 floats CONTIGUOUS in x -> flat float4 read
    const float4* src4 = (const float4*)(x + (size_t)b * (S_LEN * FE) + (size_t)s0 * FE);
    #pragma unroll
    for (int k = 0; k < 4; ++k) {
        float4 v = src4[k * 256 + tid];
        int li = (k * 256 + tid) * 4;
        int s = li >> 6, f = li & 63;
        t[s][f] = v.x; t[s][f + 1] = v.y; t[s][f + 2] = v.z; t[s][f + 3] = v.w;
    }
    __syncthreads();

    const int f  = tid >> 2;
    const int sb = (tid & 3) * 16;
    float* dst = stage + ((size_t)(b * 64 + f)) * S_LEN + s0 + sb;
    #pragma unroll
    for (int k = 0; k < 4; ++k) {
        float4 w;
        w.x = t[sb + 4 * k + 0][f];
        w.y = t[sb + 4 * k + 1][f];
        w.z = t[sb + 4 * k + 2][f];
        w.w = t[sb + 4 * k + 3][f];
        ((float4*)dst)[k] = w;
    }
}

// ---------------- kernel 3: stage (B*F, S) -> out (B,S,F) ----------------
__global__ __launch_bounds__(BT) void transpose_out(const float* __restrict__ stage,
                                                    float* __restrict__ out) {
    const int b  = blockIdx.x >> 6;
    const int s0 = (blockIdx.x & 63) << 6;
    const int tid = threadIdx.x;
    __shared__ float t[64][65];          // t[s][f]

    const int f  = tid >> 2;
    const int sb = (tid & 3) * 16;
    const float* src = stage + ((size_t)(b * 64 + f)) * S_LEN + s0 + sb;
    #pragma unroll
    for (int k = 0; k < 4; ++k) {
        float4 v = ((const float4*)src)[k];
        t[sb + 4 * k + 0][f] = v.x;
        t[sb + 4 * k + 1][f] = v.y;
        t[sb + 4 * k + 2][f] = v.z;
        t[sb + 4 * k + 3][f] = v.w;
    }
    __syncthreads();

    float4* dst4 = (float4*)(out + (size_t)b * (S_LEN * FE) + (size_t)s0 * FE);
    #pragma unroll
    for (int k = 0; k < 4; ++k) {
        int li = (k * 256 + tid) * 4;
        int s = li >> 6, fl = li & 63;
        float4 w;
        w.x = t[s][fl]; w.y = t[s][fl + 1]; w.z = t[s][fl + 2]; w.w = t[s][fl + 3];
        dst4[k * 256 + tid] = w;
    }
}

// ---------------- kernel 2: in-place row DWT-enhance ----------------
// LDS layout (floats):
//   A0[4096]: input row; after L1 the head holds a2/a4/a6/a8 and inverse
//             outputs (<=1030), tail [2009:4096] holds d2..d9 (2087).
//   AB[2052]: a1/a3/a5/a7/a9 ping-pong; inverse a-chain; a1' (2052).
//   D1[2052]: level-1 details (2051 used) — lives whole kernel.
// Total 32.9 KB -> 4 blocks/CU; VGPR capped at 64 -> 32 waves/CU.
__global__ __launch_bounds__(DT, 8) void dwt_rows_kernel(float* __restrict__ stage) {
    const int tid = threadIdx.x;
    float* __restrict__ rowp = stage + (size_t)blockIdx.x * S_LEN;

    __shared__ __align__(16) float A0[4096];
    __shared__ __align__(16) float AB[2052];
    __shared__ __align__(16) float D1[2052];
    __shared__ double redS[DT / 64], redQ[DT / 64];
    __shared__ float s_thr;

    // ---- coalesced load ----
    {
        const float4* r4 = (const float4*)rowp;
        float4* a4 = (float4*)A0;
        a4[tid]       = r4[tid];
        a4[tid + DT]  = r4[tid + DT];
    }
    __syncthreads();

    // ---- forward DWT ----
    float* src = A0;
    float* dst = AB;
    int n = S_LEN;
    for (int lev = 1; lev <= NLEV; ++lev) {
        const int na = SIZES[lev];
        float* __restrict__ dd = (lev == 1) ? D1 : (A0 + DOFF2[lev]);
        const int npair = (na + 1) >> 1;
        for (int ii = tid; ii < npair; ii += DT) {
            float w[10];
            if (ii >= 2 && 4 * ii <= n - 4) {
                const float4* p = (const float4*)(src + 4 * ii - 8);
                float4 v0 = p[0], v1 = p[1], v2 = p[2];
                w[0]=v0.z; w[1]=v0.w; w[2]=v1.x; w[3]=v1.y; w[4]=v1.z;
                w[5]=v1.w; w[6]=v2.x; w[7]=v2.y; w[8]=v2.z; w[9]=v2.w;
            } else {
                #pragma unroll
                for (int j = 0; j < 10; ++j) {
                    int q = 4 * ii + j - 6;
                    q = (q < 0) ? ~q : q;
                    q = (q >= n) ? (2 * n - 1 - q) : q;
                    w[j] = src[q];
                }
            }
            float a0 = 0.f, d0 = 0.f, a1 = 0.f, d1 = 0.f;
            #pragma unroll
            for (int j = 0; j < 8; ++j) {
                a0 = fmaf(w[j],     RL[j], a0);
                d0 = fmaf(w[j],     RH[j], d0);
                a1 = fmaf(w[j + 2], RL[j], a1);
                d1 = fmaf(w[j + 2], RH[j], d1);
            }
            const int i0 = 2 * ii;
            dst[i0] = a0; dd[i0] = d0;
            if (i0 + 1 < na) { dst[i0 + 1] = a1; dd[i0 + 1] = d1; }
        }
        // overlap sigma reduction of D1 with the small forward levels
        if (lev == 2) {
            double s = 0.0, q = 0.0;
            for (int i = tid; i < 2051; i += DT) {
                double v = (double)D1[i];
                s += v; q += v * v;
            }
            #pragma unroll
            for (int off = 32; off > 0; off >>= 1) {
                s += __shfl_down(s, off, 64);
                q += __shfl_down(q, off, 64);
            }
            if ((tid & 63) == 0) { redS[tid >> 6] = s; redQ[tid >> 6] = q; }
        }
        if (lev == 3 && tid == 0) {
            double S = 0.0, Q = 0.0;
            #pragma unroll
            for (int w2 = 0; w2 < DT / 64; ++w2) { S += redS[w2]; Q += redQ[w2]; }
            const double nd = 2051.0;
            double mean = S / nd;
            double var  = Q / nd - mean * mean;
            if (var < 0.0) var = 0.0;
            s_thr = (float)(sqrt(var) * sqrt(2.0 * log((double)S_LEN)));
        }
        __syncthreads();
        float* t = src; src = dst; dst = t;
        n = na;
    }
    // a9 in AB[0:14]

    const float thr = s_thr;

    // ---- inverse DWT (soft-threshold applied lazily at read) ----
    float* A = AB;
    float* O = A0;
    for (int lev = NLEV; lev >= 2; --lev) {
        const int nn = SIZES[lev];
        const float* __restrict__ D = A0 + DOFF2[lev];
        const int npair = nn - 3;
        const bool softA = (lev == NLEV);    // A==a9 must be thresholded
        for (int ii = tid; ii < npair; ii += DT) {
            float a0 = A[ii], a1 = A[ii + 1], a2 = A[ii + 2], a3 = A[ii + 3];
            if (softA) {
                a0 = softf(a0, thr); a1 = softf(a1, thr);
                a2 = softf(a2, thr); a3 = softf(a3, thr);
            }
            float e0 = softf(D[ii],     thr), e1 = softf(D[ii + 1], thr);
            float e2 = softf(D[ii + 2], thr), e3 = softf(D[ii + 3], thr);
            float se = a0 * RL[6] + a1 * RL[4] + a2 * RL[2] + a3 * RL[0]
                     + e0 * RH[6] + e1 * RH[4] + e2 * RH[2] + e3 * RH[0];
            float so = a0 * RL[7] + a1 * RL[5] + a2 * RL[3] + a3 * RL[1]
                     + e0 * RH[7] + e1 * RH[5] + e2 * RH[3] + e3 * RH[1];
            O[2 * ii]     = se;
            O[2 * ii + 1] = so;
        }
        __syncthreads();
        float* t = A; A = O; O = t;
    }
    // level 1 inverse: A = a1' (AB, 2051 used), D1 -> write float2 direct to global
    for (int ii = tid; ii < 2048; ii += DT) {
        float a0 = A[ii], a1 = A[ii + 1], a2 = A[ii + 2], a3 = A[ii + 3];
        float e0 = softf(D1[ii],     thr), e1 = softf(D1[ii + 1], thr);
        float e2 = softf(D1[ii + 2], thr), e3 = softf(D1[ii + 3], thr);
        float se = a0 * RL[6] + a1 * RL[4] + a2 * RL[2] + a3 * RL[0]
                 + e0 * RH[6] + e1 * RH[4] + e2 * RH[2] + e3 * RH[0];
        float so = a0 * RL[7] + a1 * RL[5] + a2 * RL[3] + a3 * RL[1]
                 + e0 * RH[7] + e1 * RH[5] + e2 * RH[3] + e3 * RH[1];
        float2 st; st.x = se; st.y = so;
        ((float2*)rowp)[ii] = st;
    }
}

// ---------------- fallback: proven monolithic kernel (strided I/O) ----------------
__global__ __launch_bounds__(BT) void dwt_enh_kernel(const float* __restrict__ x,
                                                     float* __restrict__ out) {
    const int tid = threadIdx.x;
    const int m = ((blockIdx.x & 7) << 10) | (blockIdx.x >> 3);
    const int b = m >> 6, f = m & 63;
    const float* __restrict__ rowp = x   + (size_t)b * (S_LEN * FE) + f;
    float* __restrict__       orow = out + (size_t)b * (S_LEN * FE) + f;

    __shared__ __align__(16) float bufA[4096];
    __shared__ __align__(16) float bufB[2052];
    __shared__ float dets[DTOT];
    __shared__ double redS[BT / 64], redQ[BT / 64];
    __shared__ float s_thr;

    for (int s = tid; s < S_LEN; s += BT) bufA[s] = rowp[(size_t)s * FE];
    __syncthreads();

    float* src = bufA;
    float* dst = bufB;
    int n = S_LEN;
    for (int lev = 1; lev <= NLEV; ++lev) {
        const int na = (n + 7) >> 1;
        float* __restrict__ dd = dets + DOFF[lev];
        const int npair = (na + 1) >> 1;
        for (int ii = tid; ii < npair; ii += BT) {
            float w[10];
            if (ii >= 2 && 4 * ii <= n - 4) {
                const float4* p = (const float4*)(src + 4 * ii - 8);
                float4 v0 = p[0], v1 = p[1], v2 = p[2];
                w[0]=v0.z; w[1]=v0.w; w[2]=v1.x; w[3]=v1.y; w[4]=v1.z;
                w[5]=v1.w; w[6]=v2.x; w[7]=v2.y; w[8]=v2.z; w[9]=v2.w;
            } else {
                #pragma unroll
                for (int j = 0; j < 10; ++j) {
                    int q = 4 * ii + j - 6;
                    q = (q < 0) ? ~q : q;
                    q = (q >= n) ? (2 * n - 1 - q) : q;
                    w[j] = src[q];
                }
            }
            float a0 = 0.f, d0 = 0.f, a1 = 0.f, d1 = 0.f;
            #pragma unroll
            for (int j = 0; j < 8; ++j) {
                a0 = fmaf(w[j],     RL[j], a0);
                d0 = fmaf(w[j],     RH[j], d0);
                a1 = fmaf(w[j + 2], RL[j], a1);
                d1 = fmaf(w[j + 2], RH[j], d1);
            }
            const int i0 = 2 * ii;
            dst[i0] = a0; dd[i0] = d0;
            if (i0 + 1 < na) { dst[i0 + 1] = a1; dd[i0 + 1] = d1; }
        }
        __syncthreads();
        float* t = src; src = dst; dst = t;
        n = na;
    }

    {
        double s = 0.0, q = 0.0;
        for (int i = tid; i < 2051; i += BT) {
            double v = (double)dets[i];
            s += v; q += v * v;
        }
        #pragma unroll
        for (int off = 32; off > 0; off >>= 1) {
            s += __shfl_down(s, off, 64);
            q += __shfl_down(q, off, 64);
        }
        const int wid = tid >> 6, lane = tid & 63;
        if (lane == 0) { redS[wid] = s; redQ[wid] = q; }
        __syncthreads();
        if (tid == 0) {
            double S = 0.0, Q = 0.0;
            #pragma unroll
            for (int w2 = 0; w2 < BT / 64; ++w2) { S += redS[w2]; Q += redQ[w2]; }
            const double nd = 2051.0;
            double mean = S / nd;
            double var  = Q / nd - mean * mean;
            if (var < 0.0) var = 0.0;
            s_thr = (float)(sqrt(var) * sqrt(2.0 * log((double)S_LEN)));
        }
        __syncthreads();
    }
    const float thr = s_thr;

    for (int i = tid; i < DTOT; i += BT) dets[i] = softf(dets[i], thr);
    if (tid < 14) src[tid] = softf(src[tid], thr);
    __syncthreads();

    float* A = src;
    float* O = (A == bufA) ? bufB : bufA;
    for (int lev = NLEV; lev >= 1; --lev) {
        const int nn = SIZES[lev];
        const float* __restrict__ D = dets + DOFF[lev];
        const int npair = nn - 3;
        for (int ii = tid; ii < npair; ii += BT) {
            float a0 = A[ii], a1 = A[ii + 1], a2 = A[ii + 2], a3 = A[ii + 3];
            float e0 = D[ii], e1 = D[ii + 1], e2 = D[ii + 2], e3 = D[ii + 3];
            float se = a0 * RL[6] + a1 * RL[4] + a2 * RL[2] + a3 * RL[0]
                     + e0 * RH[6] + e1 * RH[4] + e2 * RH[2] + e3 * RH[0];
            float so = a0 * RL[7] + a1 * RL[5] + a2 * RL[3] + a3 * RL[1]
                     + e0 * RH[7] + e1 * RH[5] + e2 * RH[3] + e3 * RH[1];
            O[2 * ii]     = se;
            O[2 * ii + 1] = so;
        }
        __syncthreads();
        float* t = A; A = O; O = t;
    }

    for (int s = tid; s < S_LEN; s += BT) orow[(size_t)s * FE] = A[s];
}

extern "C" void kernel_launch(void* const* d_in, const int* in_sizes, int n_in,
                              void* d_out, int out_size, void* d_ws, size_t ws_size,
                              hipStream_t stream) {
    const float* x = (const float*)d_in[0];
    float* out = (float*)d_out;
    const size_t need = (size_t)NROWS * S_LEN * sizeof(float);   // 128 MiB
    if (ws_size >= need) {
        float* stage = (float*)d_ws;
        hipLaunchKernelGGL(transpose_in,  dim3(NROWS), dim3(BT), 0, stream, x, stage);
        hipLaunchKernelGGL(dwt_rows_kernel, dim3(NROWS), dim3(DT), 0, stream, stage);
        hipLaunchKernelGGL(transpose_out, dim3(NROWS), dim3(BT), 0, stream, stage, out);
    } else {
        hipLaunchKernelGGL(dwt_enh_kernel, dim3(NROWS), dim3(BT), 0, stream, x, out);
    }
}